// Round 6
// baseline (678.254 us; speedup 1.0000x reference)
//
#include <hip/hip_runtime.h>
#include <math.h>

#define HIDDEN 2048
#define NHEAD 16
#define HD 128
#define SEQ 2048
#define BATCH 2
#define MROWS (BATCH * SEQ)   // 4096
#define K3 (3 * HIDDEN)       // 6144

#define SCORE_SCALE 0.08838834764831845f  // 1/sqrt(128), LAYER_NUMBER=1

using short8 = __attribute__((ext_vector_type(8))) short;
using f32x4 = __attribute__((ext_vector_type(4))) float;

__device__ __forceinline__ unsigned short f2bf(float f) {
  union { float f; unsigned int u; } v; v.f = f;
  const unsigned int u = v.u;
  return (unsigned short)((u + 0x7FFFu + ((u >> 16) & 1u)) >> 16);
}

// async 16B global -> LDS (global addr per-lane; LDS dest uniform base + lane*16)
__device__ __forceinline__ void gl2lds16(const void* g, void* l) {
#pragma clang diagnostic push
#pragma clang diagnostic ignored "-Waddress-space-conversion"
  __builtin_amdgcn_global_load_lds(
      (const __attribute__((address_space(1))) unsigned int*)g,
      (__attribute__((address_space(3))) unsigned int*)l, 16, 0, 0);
#pragma clang diagnostic pop
}

// ---------------------------------------------------------------------------
// fp32 -> bf16 convert, all three tensors in one launch (8 elems/thread)
// ---------------------------------------------------------------------------
__global__ __launch_bounds__(256) void cvt_all(
    const float* __restrict__ s0, unsigned short* __restrict__ d0, int n0,
    const float* __restrict__ s1, unsigned short* __restrict__ d1, int n1,
    const float* __restrict__ s2, unsigned short* __restrict__ d2, int n2) {
  int i = (blockIdx.x * 256 + threadIdx.x) * 8;
  const float* src;
  unsigned short* dst;
  if (i < n0) {
    src = s0; dst = d0;
  } else if (i < n0 + n1) {
    src = s1; dst = d1; i -= n0;
  } else {
    src = s2; dst = d2; i -= n0 + n1;
    if (i >= n2) return;
  }
  const float4 a = *(const float4*)(src + i);
  const float4 b = *(const float4*)(src + i + 4);
  ushort4 oa, ob;
  oa.x = f2bf(a.x); oa.y = f2bf(a.y); oa.z = f2bf(a.z); oa.w = f2bf(a.w);
  ob.x = f2bf(b.x); ob.y = f2bf(b.y); ob.z = f2bf(b.z); ob.w = f2bf(b.w);
  *(ushort4*)(dst + i) = oa;
  *(ushort4*)(dst + i + 4) = ob;
}

// ---------------------------------------------------------------------------
// MFMA bf16 GEMM (m97 structure): C[m,n] = sum_k A[m,k]*W[n,k]
// 1D grid, 4x4-supertile block swizzle: 16 consecutive block IDs cover a
// 512x512 output patch (0.5 MB A + 0.5 MB W working set -> L2-resident tile
// re-reads; was a 48-tile n-sweep = 25 MB concurrent W working set).
// NPN = patches per n-row (n_tiles/4).
// MODE 0: +bias; q,k bf16 natural [B,NH,S,HD]; v in PV-fragment-ready tiled
//   layout vt4[bh][nt(8)][ksup(64)][qq(4)][dl(16)][8] (packed ushort4 stores).
// MODE 1: +bias+residual fp32 out.
// ---------------------------------------------------------------------------
template <int MODE, int NPN>
__global__ __launch_bounds__(256) void gemm_mfma(
    const unsigned short* __restrict__ A, const unsigned short* __restrict__ W,
    const float* __restrict__ bias, const float* __restrict__ residual,
    unsigned short* __restrict__ q, unsigned short* __restrict__ k,
    unsigned short* __restrict__ v, float* __restrict__ outf, int K) {
  __shared__ __align__(16) unsigned short As[128 * 32];
  __shared__ __align__(16) unsigned short Bs[128 * 32];
  const int tid = threadIdx.x;
  const int lane = tid & 63;
  const int wave = tid >> 6;
  const int l15 = lane & 15;
  const int quad = lane >> 4;
  const int wr = wave >> 1, wc = wave & 1;
  // 4x4 supertile swizzle
  const int bid = blockIdx.x;
  const int p = bid >> 4, off = bid & 15;
  const int pr = p / NPN, pc = p % NPN;
  const int m0 = ((pr << 2) + (off >> 2)) << 7;
  const int n0 = ((pc << 2) + (off & 3)) << 7;

  f32x4 acc[4][4];
#pragma unroll
  for (int i = 0; i < 4; ++i)
#pragma unroll
    for (int j = 0; j < 4; ++j) {
      f32x4 z = {0.f, 0.f, 0.f, 0.f};
      acc[i][j] = z;
    }

  const int kg0 = tid >> 7, mr0 = tid & 127;
  const int kg1 = (tid + 256) >> 7, mr1 = tid & 127;

  for (int k0 = 0; k0 < K; k0 += 32) {
    gl2lds16(A + (size_t)(m0 + mr0) * K + k0 + kg0 * 8, (char*)As + tid * 16);
    gl2lds16(W + (size_t)(n0 + mr0) * K + k0 + kg0 * 8, (char*)Bs + tid * 16);
    gl2lds16(A + (size_t)(m0 + mr1) * K + k0 + kg1 * 8,
             (char*)As + 4096 + tid * 16);
    gl2lds16(W + (size_t)(n0 + mr1) * K + k0 + kg1 * 8,
             (char*)Bs + 4096 + tid * 16);
    __syncthreads();
    short8 af[4], bf[4];
#pragma unroll
    for (int i = 0; i < 4; ++i)
      af[i] = *(const short8*)((const char*)As + quad * 2048 +
                               (wr * 64 + i * 16 + l15) * 16);
#pragma unroll
    for (int j = 0; j < 4; ++j)
      bf[j] = *(const short8*)((const char*)Bs + quad * 2048 +
                               (wc * 64 + j * 16 + l15) * 16);
#pragma unroll
    for (int i = 0; i < 4; ++i)
#pragma unroll
      for (int j = 0; j < 4; ++j)
        acc[i][j] =
            __builtin_amdgcn_mfma_f32_16x16x32_bf16(af[i], bf[j], acc[i][j],
                                                    0, 0, 0);
    __syncthreads();
  }

  if (MODE == 0) {
#pragma unroll
    for (int i = 0; i < 4; ++i) {
#pragma unroll
      for (int j = 0; j < 4; ++j) {
        const int n = n0 + wc * 64 + j * 16 + l15;
        const float bi = bias[n];
        const int h = n / 384;
        const int rem = n - h * 384;
        const int which = rem >> 7;
        const int d = rem & 127;
        const int mb = m0 + wr * 64 + i * 16 + quad * 4;  // mb % 4 == 0
        const int bb = mb >> 11, ssb = mb & 2047;
        const int bh = (bb << 4) + h;
        if (which == 2) {
          // vt4 packed store: 4 consecutive k (=s) in one ushort4
          const int dt = d >> 4, dl = d & 15;
          const int ksup = ssb >> 5, ntl = (ssb >> 4) & 1, qq = (ssb >> 2) & 3;
          ushort4 pk;
          pk.x = f2bf(acc[i][j][0] + bi);
          pk.y = f2bf(acc[i][j][1] + bi);
          pk.z = f2bf(acc[i][j][2] + bi);
          pk.w = f2bf(acc[i][j][3] + bi);
          *(ushort4*)(v +
                      ((((size_t)(bh * 8 + dt) * (SEQ / 32) + ksup) * 4 + qq) *
                       16 + dl) * 8 + ntl * 4) = pk;
        } else {
          unsigned short* dst = (which == 0) ? q : k;
#pragma unroll
          for (int p2 = 0; p2 < 4; ++p2)
            dst[((size_t)(bh << 11) + ssb + p2) * HD + d] =
                f2bf(acc[i][j][p2] + bi);
        }
      }
    }
  } else {
#pragma unroll
    for (int i = 0; i < 4; ++i) {
#pragma unroll
      for (int j = 0; j < 4; ++j) {
        const int n = n0 + wc * 64 + j * 16 + l15;
        const float bi = bias[n];
#pragma unroll
        for (int p2 = 0; p2 < 4; ++p2) {
          const int m = m0 + wr * 64 + i * 16 + quad * 4 + p2;
          outf[(size_t)m * HIDDEN + n] =
              acc[i][j][p2] + bi + residual[(size_t)m * HIDDEN + n];
        }
      }
    }
  }
}

// ---------------------------------------------------------------------------
// Hybrid MFMA flash attention v2 (causal + alibi). Block = 128 q-rows of one
// (head,batch); wave w owns 32 q-rows (2 halves of 16). K-tile = 64, shared
// across waves via LDS (frag-order staging). Each kf/vf LDS read now feeds
// TWO MFMAs (ratio 0.5 read:MFMA, was 1:1) and staging traffic per q-row is
// halved. Softmax in registers (per half: in-lane + 2 shfl_xor). P packed
// in-lane with relabeled PV k-slots. Per-wave causal skip: wave w's diagonal
// k-tile is dlim = 2bt + (w>>1); kt > dlim skipped (wave-uniform); diagonal
// tile computes ntmax = (w&1)?4:2 k-subtiles.
// LDS = 32 KB; grid 512 blocks = 2 blocks/CU (matches ~170 VGPR occupancy).
// ---------------------------------------------------------------------------
__global__ __launch_bounds__(256) void attn_mfma4(
    const unsigned short* __restrict__ qb, const unsigned short* __restrict__ kb,
    const unsigned short* __restrict__ vt4, unsigned short* __restrict__ ctx) {
  __shared__ __align__(16) unsigned short Ks[8192];  // [nt4][dt4][quad4][l15:16][8]
  __shared__ __align__(16) unsigned short Vs[8192];  // [nt8][s2:2][quad4][l15:16][8]

  const int tid = threadIdx.x;
  const int lane = tid & 63;
  const int w = tid >> 6;
  const int l15 = lane & 15;
  const int quad = lane >> 4;
  const int bt = gridDim.x - 1 - blockIdx.x;  // heavy tiles first
  const int q0 = bt << 7;
  const int h = blockIdx.y, b = blockIdx.z;
  const int bh = b * NHEAD + h;
  const float slope = exp2f(-0.5f * (float)(h + 1));
  const unsigned short* qp = qb + ((size_t)bh * SEQ + q0 + w * 32) * HD;
  const unsigned short* kp = kb + (size_t)bh * SEQ * HD;
  const unsigned short* vp = vt4 + (size_t)bh * SEQ * HD;

  // Q B-frags (persist): halves u=0,1; lane n=l15 -> q-row qlo+u*16+l15
  short8 qf[4][2];
#pragma unroll
  for (int dt = 0; dt < 4; ++dt)
#pragma unroll
    for (int u = 0; u < 2; ++u)
      qf[dt][u] =
          *(const short8*)(qp + (size_t)(u * 16 + l15) * HD + dt * 32 + quad * 8);

  f32x4 O0[8], O1[8];
#pragma unroll
  for (int i = 0; i < 8; ++i) {
    f32x4 z = {0.f, 0.f, 0.f, 0.f};
    O0[i] = z;
    O1[i] = z;
  }
  float mrow0 = -3.0e38f, lrow0 = 0.f;
  float mrow1 = -3.0e38f, lrow1 = 0.f;
  const int qlo = q0 + w * 32;
  const int qg0 = qlo + l15, qg1 = qlo + 16 + l15;
  const int dlim = 2 * bt + (w >> 1);  // wave's diagonal k-tile
  const int ktend = 2 * bt + 1;

  for (int kt = 0; kt <= ktend; ++kt) {
    // ---- stage K tile into frag order ----
#pragma unroll
    for (int p = 0; p < 4; ++p) {
      const int idx = tid + p * 256;
      const int reg = idx >> 6;
      const int nts = reg >> 2, dts = reg & 3;
      const int qs = (idx >> 4) & 3, ls = idx & 15;
      gl2lds16(kp + (size_t)(kt * 64 + nts * 16 + ls) * HD + dts * 32 + qs * 8,
               (char*)Ks + idx * 16);
    }
    // ---- stage V tile: flat copy of contiguous vt4 chunks ----
#pragma unroll
    for (int p = 0; p < 4; ++p) {
      const int idx = tid + p * 256;
      const int ntv = idx >> 7, off = idx & 127;
      gl2lds16(vp + ((size_t)(ntv * 64 + kt * 2)) * 512 + off * 8,
               (char*)Vs + idx * 16);
    }
    __syncthreads();  // tiles ready

    if (kt <= dlim) {  // wave-uniform causal skip
      const bool diag = (kt == dlim);
      const int ntmax = diag ? ((w & 1) ? 4 : 2) : 4;
      const int kbase = kt << 6;

      // ---- S^T = K·Q^T : kf read once, 2 MFMAs (both q-halves) ----
      f32x4 sc0[4], sc1[4];
#pragma unroll
      for (int nt = 0; nt < 4; ++nt) {
        f32x4 z = {0.f, 0.f, 0.f, 0.f};
        sc0[nt] = z;
        sc1[nt] = z;
      }
#pragma unroll
      for (int dt = 0; dt < 4; ++dt) {
#pragma unroll
        for (int nt = 0; nt < 4; ++nt) {
          if (nt < ntmax) {
            const short8 kf = *(const short8*)(
                (const char*)Ks +
                ((((nt * 4 + dt) * 4 + quad) * 16 + l15) << 4));
            sc0[nt] = __builtin_amdgcn_mfma_f32_16x16x32_bf16(kf, qf[dt][0],
                                                              sc0[nt], 0, 0, 0);
            sc1[nt] = __builtin_amdgcn_mfma_f32_16x16x32_bf16(kf, qf[dt][1],
                                                              sc1[nt], 0, 0, 0);
          }
        }
      }

      // ---- scale + alibi + causal mask; in-lane max (per half) ----
      float pm0 = -3.0e38f, pm1 = -3.0e38f;
#pragma unroll
      for (int nt = 0; nt < 4; ++nt) {
        const int kb2 = kbase + nt * 16 + quad * 4;
#pragma unroll
        for (int r = 0; r < 4; ++r) {
          const int kg = kb2 + r;
          const float ab = slope * (float)kg;
          float s0 = fmaf(sc0[nt][r], SCORE_SCALE, ab);
          float s1 = fmaf(sc1[nt][r], SCORE_SCALE, ab);
          if (diag && kg > qg0) s0 = -1.0e30f;
          if (diag && kg > qg1) s1 = -1.0e30f;
          sc0[nt][r] = s0;
          sc1[nt][r] = s1;
          pm0 = fmaxf(pm0, s0);
          pm1 = fmaxf(pm1, s1);
        }
      }
      pm0 = fmaxf(pm0, __shfl_xor(pm0, 16, 64));
      pm0 = fmaxf(pm0, __shfl_xor(pm0, 32, 64));
      pm1 = fmaxf(pm1, __shfl_xor(pm1, 16, 64));
      pm1 = fmaxf(pm1, __shfl_xor(pm1, 32, 64));
      const float mn0 = fmaxf(mrow0, pm0);
      const float mn1 = fmaxf(mrow1, pm1);
      const float alpha0 = __expf(mrow0 - mn0);
      const float alpha1 = __expf(mrow1 - mn1);
      mrow0 = mn0;
      mrow1 = mn1;
      float rs0 = 0.f, rs1 = 0.f;
#pragma unroll
      for (int nt = 0; nt < 4; ++nt)
#pragma unroll
        for (int r = 0; r < 4; ++r) {
          const float p0 = __expf(sc0[nt][r] - mn0);
          const float p1 = __expf(sc1[nt][r] - mn1);
          sc0[nt][r] = p0;
          sc1[nt][r] = p1;
          rs0 += p0;
          rs1 += p1;
        }
      rs0 += __shfl_xor(rs0, 16, 64);
      rs0 += __shfl_xor(rs0, 32, 64);
      rs1 += __shfl_xor(rs1, 16, 64);
      rs1 += __shfl_xor(rs1, 32, 64);
      lrow0 = lrow0 * alpha0 + rs0;
      lrow1 = lrow1 * alpha1 + rs1;

      // alpha for O rows (q = quad*4+r): fetch from in-group lane quad*4+r
      float a0[4], a1[4];
#pragma unroll
      for (int r = 0; r < 4; ++r) {
        const int srcl = (quad << 4) + (quad << 2) + r;
        a0[r] = __shfl(alpha0, srcl, 64);
        a1[r] = __shfl(alpha1, srcl, 64);
      }
#pragma unroll
      for (int o = 0; o < 8; ++o)
#pragma unroll
        for (int r = 0; r < 4; ++r) {
          O0[o][r] *= a0[r];
          O1[o][r] *= a1[r];
        }

      // ---- pack P into A-frags (in-lane; relabeled k-slots) ----
      union { short8 s; unsigned int u[4]; } pf0[2], pf1[2];
#pragma unroll
      for (int nt = 0; nt < 4; ++nt) {
        pf0[nt >> 1].u[(nt & 1) * 2] =
            (unsigned int)f2bf(sc0[nt][0]) | ((unsigned int)f2bf(sc0[nt][1]) << 16);
        pf0[nt >> 1].u[(nt & 1) * 2 + 1] =
            (unsigned int)f2bf(sc0[nt][2]) | ((unsigned int)f2bf(sc0[nt][3]) << 16);
        pf1[nt >> 1].u[(nt & 1) * 2] =
            (unsigned int)f2bf(sc1[nt][0]) | ((unsigned int)f2bf(sc1[nt][1]) << 16);
        pf1[nt >> 1].u[(nt & 1) * 2 + 1] =
            (unsigned int)f2bf(sc1[nt][2]) | ((unsigned int)f2bf(sc1[nt][3]) << 16);
      }

      // ---- PV: vf read once, 2 MFMAs (both halves) ----
#pragma unroll
      for (int s2 = 0; s2 < 2; ++s2) {
#pragma unroll
        for (int nt = 0; nt < 8; ++nt) {
          const short8 vf = *(const short8*)(
              (const char*)Vs + nt * 2048 + s2 * 1024 + quad * 256 + l15 * 16);
          O0[nt] = __builtin_amdgcn_mfma_f32_16x16x32_bf16(pf0[s2].s, vf,
                                                           O0[nt], 0, 0, 0);
          O1[nt] = __builtin_amdgcn_mfma_f32_16x16x32_bf16(pf1[s2].s, vf,
                                                           O1[nt], 0, 0, 0);
        }
      }
    }
    __syncthreads();  // LDS reads done before next staging overwrites
  }

  // ---- epilogue: O /= l, write ctx [B,S,H] bf16 ----
  const float li0 = 1.f / lrow0;
  const float li1 = 1.f / lrow1;
  float i0[4], i1[4];
#pragma unroll
  for (int r = 0; r < 4; ++r) {
    const int srcl = (quad << 4) + (quad << 2) + r;
    i0[r] = __shfl(li0, srcl, 64);
    i1[r] = __shfl(li1, srcl, 64);
  }
#pragma unroll
  for (int nt = 0; nt < 8; ++nt)
#pragma unroll
    for (int r = 0; r < 4; ++r) {
      const size_t row = (size_t)b * SEQ + qlo + quad * 4 + r;
      ctx[(row)*HIDDEN + h * HD + nt * 16 + l15] = f2bf(O0[nt][r] * i0[r]);
      ctx[(row + 16) * HIDDEN + h * HD + nt * 16 + l15] =
          f2bf(O1[nt][r] * i1[r]);
    }
}

// ---------------------------------------------------------------------------
extern "C" void kernel_launch(void* const* d_in, const int* in_sizes, int n_in,
                              void* d_out, int out_size, void* d_ws,
                              size_t ws_size, hipStream_t stream) {
  const float* hs = (const float*)d_in[0];
  const float* res = (const float*)d_in[1];
  // d_in[2] attention_mask: all ones -> causal only
  const float* Wqkv = (const float*)d_in[3];
  const float* bqkv = (const float*)d_in[4];
  const float* Wd = (const float*)d_in[5];
  const float* bd = (const float*)d_in[6];
  float* out = (float*)d_out;

  const size_t per = (size_t)BATCH * NHEAD * SEQ * HD;  // 8.39M elems
  const size_t n_hs = (size_t)MROWS * HIDDEN;
  const size_t n_wq = (size_t)K3 * HIDDEN;
  const size_t n_wd = (size_t)HIDDEN * HIDDEN;

  unsigned short* ws = (unsigned short*)d_ws;
  unsigned short* qb = ws;
  unsigned short* kb = qb + per;
  unsigned short* vtb = kb + per;  // v in PV-fragment tiled layout (vt4)
  unsigned short* ctxb = vtb + per;
  unsigned short* hs_bf = ctxb + n_hs;
  unsigned short* wq_bf = hs_bf + n_hs;
  unsigned short* wd_bf = wq_bf + n_wq;

  dim3 blk(256);
  const unsigned cvt_blocks = (unsigned)((n_hs + n_wq + n_wd) / 8 / 256);
  cvt_all<<<dim3(cvt_blocks), blk, 0, stream>>>(
      hs, hs_bf, (int)n_hs, Wqkv, wq_bf, (int)n_wq, Wd, wd_bf, (int)n_wd);
  // QKV: 32 m-tiles x 48 n-tiles = 1536 blocks; patches/row = 48/4 = 12
  gemm_mfma<0, 12><<<dim3(1536), blk, 0, stream>>>(
      hs_bf, wq_bf, bqkv, nullptr, qb, kb, vtb, nullptr, HIDDEN);
  attn_mfma4<<<dim3(SEQ / 128, NHEAD, BATCH), blk, 0, stream>>>(qb, kb, vtb,
                                                                ctxb);
  // dense: 32 m-tiles x 16 n-tiles = 512 blocks; patches/row = 16/4 = 4
  gemm_mfma<1, 4><<<dim3(512), blk, 0, stream>>>(
      ctxb, wd_bf, bd, res, nullptr, nullptr, nullptr, out, HIDDEN);
}